// Round 7
// baseline (103.995 us; speedup 1.0000x reference)
//
#include <hip/hip_runtime.h>

// Disable FMA contraction so float rounding matches the numpy reference
// op-for-op (threshold compares at 0.5 and argmax ties depend on it).
#pragma clang fp contract(off)

#define BB 32     // batch
#define NN 100    // gt boxes per image
#define PP 8732   // priors
#define CH 16     // j-chunk for the transposed row-max reduce
#define LDW 257   // padded row stride (u32) -> 2-way banks only (free)
#define NBX 35    // blocks along the prior axis

// -------------------------------------------------------------------------
// Encode helper: SSD box encoding of gt box g vs prior pr (cxcywh).
// Bit-identical to the reference op order (contract off).
// -------------------------------------------------------------------------
__device__ __forceinline__ float4 encode_box(float4 g, float4 pr) {
    const float mcx = (g.x + g.z) * 0.5f;
    const float mcy = (g.y + g.w) * 0.5f;
    const float mw  = fmaxf(g.z - g.x, 1e-6f);
    const float mh  = fmaxf(g.w - g.y, 1e-6f);
    return make_float4((mcx - pr.x) / (0.1f * pr.z),
                       (mcy - pr.y) / (0.1f * pr.w),
                       logf(mw / pr.z) / 0.2f,
                       logf(mh / pr.w) / 0.2f);
}

// -------------------------------------------------------------------------
// Kernel 1: thread owns prior p of batch b. Computes the full N x P IoU
// once, tracks column max/argmax (strict > = first occurrence) in regs,
// reduces row max via the chunked LDS transpose into per-block u64 keys
// ((iou_bits<<32)|~p : max == max-iou then min-p), and writes the FINAL
// loc/conf assuming no forced match (true for all but <=100 priors per
// batch; k_patch rewrites those afterwards).
// Out-of-range lanes compute the real IoU of prior PP-1: duplicate columns
// tie with p=8731's value and lose the min-p tie-break, so no pw >= PP can
// ever win a row (verified round 6).
// -------------------------------------------------------------------------
template <bool USE_PART>
__global__ __launch_bounds__(256) void k_iou_pass(
    const float* __restrict__ gt,        // [B,N,4] xyxy
    const int*   __restrict__ labels,    // [B,N]
    const float* __restrict__ priors,    // [P,4] cxcywh
    unsigned long long* __restrict__ red,   // part [B][NBX][NN] or gkey [B][N]
    float* __restrict__ loc_out,         // [B,P,4]
    float* __restrict__ conf_out)        // [B,P]
{
    __shared__ unsigned int s_iou[CH * LDW];          // 16.4 KB
    __shared__ unsigned long long s_part[NN][17];     // 13.6 KB
    __shared__ float s_area[NN];                      // 400 B

    const int b = blockIdx.y;
    const int t = threadIdx.x;
    const int p = blockIdx.x * 256 + t;
    const bool valid = p < PP;
    const int pc = valid ? p : (PP - 1);

    // wave-uniform base: compiler scalarizes these loads (s_load_dwordx4)
    const float4* __restrict__ gtb =
        reinterpret_cast<const float4*>(gt) + b * NN;

    if (t < NN) {
        float4 g = gtb[t];
        s_area[t] = (g.z - g.x) * (g.w - g.y);
    }

    const float4 pr = reinterpret_cast<const float4*>(priors)[pc];
    const float px1 = pr.x - pr.z * 0.5f;
    const float py1 = pr.y - pr.w * 0.5f;
    const float px2 = pr.x + pr.z * 0.5f;
    const float py2 = pr.y + pr.w * 0.5f;
    const float area_b = (px2 - px1) * (py2 - py1);

    float best_ov = -1.0f;
    int best_j = 0;

    __syncthreads();   // s_area ready

    for (int jc = 0; jc < NN; jc += CH) {
        const int nr = (NN - jc) < CH ? (NN - jc) : CH;

        #pragma unroll
        for (int jj = 0; jj < CH; ++jj) {
            if (jj >= nr) break;
            float4 g = gtb[jc + jj];                 // uniform -> SGPRs
            float area_a = s_area[jc + jj];          // broadcast ds_read
            float ltx = fmaxf(g.x, px1), lty = fmaxf(g.y, py1);
            float rbx = fminf(g.z, px2), rby = fminf(g.w, py2);
            float w = fmaxf(rbx - ltx, 0.0f), h = fmaxf(rby - lty, 0.0f);
            float inter = w * h;
            float iou = inter / (area_a + area_b - inter + 1e-6f);
            if (iou > best_ov) { best_ov = iou; best_j = jc + jj; }
            s_iou[jj * LDW + t] = __float_as_uint(iou);  // iou>=0: uint order
        }
        __syncthreads();

        // phase A: 16 threads per row, each scans 16 ascending-p columns
        {
            const int r = t & 15;
            const int s = t >> 4;
            if (r < nr) {
                const unsigned int* row = s_iou + r * LDW + s * 16;
                unsigned int bb = row[0];
                int bi = 0;
                #pragma unroll
                for (int i = 1; i < 16; ++i) {
                    unsigned int v = row[i];
                    if (v > bb) { bb = v; bi = i; }   // strict > = min p
                }
                int pw = blockIdx.x * 256 + s * 16 + bi;
                s_part[jc + r][s] = ((unsigned long long)bb << 32) |
                                    (unsigned int)(~pw);
            }
        }
        __syncthreads();   // s_iou reusable next chunk; s_part visible
    }

    // phase B: merge 16 segment partials per gt; plain store (or atomic)
    if (t < NN) {
        unsigned long long best = s_part[t][0];
        #pragma unroll
        for (int s = 1; s < 16; ++s) {
            unsigned long long k = s_part[t][s];
            if (k > best) best = k;                   // ~p breaks iou ties
        }
        if (USE_PART) {
            red[((size_t)b * NBX + blockIdx.x) * NN + t] = best;
        } else {
            atomicMax(&red[b * NN + t], best);
        }
    }

    // fused encode (non-forced assumption; k_patch rewrites forced priors)
    if (valid) {
        const int lab  = labels[b * NN + best_j];
        const int conf = (best_ov < 0.5f) ? 0 : (lab + 1);
        const float4 g = gtb[best_j];    // divergent gather, L1-hot
        reinterpret_cast<float4*>(loc_out)[b * PP + p] = encode_box(g, pr);
        conf_out[b * PP + p] = (float)conf;
    }
}

// -------------------------------------------------------------------------
// Kernel 2 (micro): one block per batch. Reduce the NBX per-block row keys
// per gt, resolve duplicate winning priors by max j (last-write-wins,
// matching the reference scatter), and rewrite ONLY the forced priors.
// -------------------------------------------------------------------------
template <bool USE_PART>
__global__ __launch_bounds__(128) void k_patch(
    const float* __restrict__ gt,        // [B,N,4]
    const int*   __restrict__ labels,    // [B,N]
    const float* __restrict__ priors,    // [P,4]
    const unsigned long long* __restrict__ red,   // part or gkey
    float* __restrict__ loc_out,         // [B,P,4]
    float* __restrict__ conf_out)        // [B,P]
{
    __shared__ int s_kp[NN];

    const int b = blockIdx.x;
    const int t = threadIdx.x;

    int kp = -1;
    if (t < NN) {
        unsigned long long best;
        if (USE_PART) {
            const unsigned long long* q = red + (size_t)b * NBX * NN + t;
            best = q[0];
            #pragma unroll 5
            for (int bx = 1; bx < NBX; ++bx) {
                unsigned long long k = q[(size_t)bx * NN];
                if (k > best) best = k;               // ~p breaks iou ties
            }
        } else {
            best = red[b * NN + t];
        }
        kp = (int)~(unsigned int)(best & 0xFFFFFFFFull);
        s_kp[t] = kp;
    }
    __syncthreads();

    if (t < NN) {
        // last-write-wins: gt t owns prior kp iff no later gt also won it
        bool win = true;
        for (int u = t + 1; u < NN; ++u)
            if (s_kp[u] == kp) { win = false; break; }
        if (win) {
            const float4 g  = reinterpret_cast<const float4*>(gt)[b * NN + t];
            const float4 pr = reinterpret_cast<const float4*>(priors)[kp];
            reinterpret_cast<float4*>(loc_out)[b * PP + kp] = encode_box(g, pr);
            conf_out[b * PP + kp] = (float)(labels[b * NN + t] + 1);
        }
    }
}

extern "C" void kernel_launch(void* const* d_in, const int* in_sizes, int n_in,
                              void* d_out, int out_size, void* d_ws, size_t ws_size,
                              hipStream_t stream) {
    const float* gt     = (const float*)d_in[0];  // [32,100,4] f32
    const int*   labels = (const int*)  d_in[1];  // [32,100] i32
    const float* priors = (const float*)d_in[2];  // [8732,4] f32

    float* loc  = (float*)d_out;                         // [32,8732,4]
    float* conf = (float*)d_out + (size_t)BB * PP * 4;   // [32,8732]

    const size_t part_bytes = (size_t)BB * NBX * NN * 8;   // 896,000
    dim3 grid(NBX, BB);

    if (ws_size >= part_bytes) {
        // atomic-free path: per-block partial keys, no memset dispatch
        unsigned long long* part = (unsigned long long*)d_ws;
        k_iou_pass<true><<<grid, 256, 0, stream>>>(gt, labels, priors, part,
                                                   loc, conf);
        k_patch<true><<<BB, 128, 0, stream>>>(gt, labels, priors, part,
                                              loc, conf);
    } else {
        // fallback: gkey + atomicMax (needs zeroed keys)
        unsigned long long* gkey = (unsigned long long*)d_ws;        // [32,100]
        hipMemsetAsync(gkey, 0, (size_t)BB * NN * 8, stream);
        k_iou_pass<false><<<grid, 256, 0, stream>>>(gt, labels, priors, gkey,
                                                    loc, conf);
        k_patch<false><<<BB, 128, 0, stream>>>(gt, labels, priors, gkey,
                                               loc, conf);
    }
}

// Round 8
// 100.246 us; speedup vs baseline: 1.0374x; 1.0374x over previous
//
#include <hip/hip_runtime.h>

// Disable FMA contraction so float rounding matches the numpy reference
// op-for-op (threshold compares at 0.5 and argmax ties depend on it).
#pragma clang fp contract(off)

#define BB 32     // batch
#define NN 100    // gt boxes per image
#define PP 8732   // priors
#define CH 16     // j-chunk for the transposed row-max reduce
#define LDW 257   // padded row stride (u32) -> 2-way banks only (free)
#define NBK 18    // k_iou blocks along the prior axis (512-wide strips)
#define NBX 35    // k_encode blocks along the prior axis (256-wide)

// -------------------------------------------------------------------------
// Kernel 1: thread owns priors p0 = bx*512+t and p1 = p0+256 of batch b.
// The wave-uniform gt scalar load and the s_area ds_read are shared by two
// independent IoU chains (ILP). Column max/argmax per prior in regs
// (strict > = first occurrence) -> m8 bytes. Row max via two 16x257 LDS
// transpose buffers (2-way banks = free); phase A scans 16 ascending-p
// cols per strip, merges the two strips' u64 keys ((iou<<32)|~p : max ==
// max-iou then min-p; strip0 pw < strip1 pw so ties resolve to min p),
// stores to shared s_part[j][seg]; phase B merges 16 segs and plain-stores
// the per-block key (USE_PART) or atomicMax (fallback).
// Out-of-range lanes compute the real IoU of prior PP-1: duplicates carry
// its exact value and lose the ~p tie-break, so no pw >= PP can win
// (verified rounds 5-6).
// -------------------------------------------------------------------------
template <bool USE_PART>
__global__ __launch_bounds__(256) void k_iou_pass(
    const float* __restrict__ gt,        // [B,N,4] xyxy
    const float* __restrict__ priors,    // [P,4] cxcywh
    unsigned long long* __restrict__ red,   // part [B][NBK][NN] or gkey [B][N]
    unsigned char* __restrict__ m8)         // [B,P]: best_j | (bg?0x80:0)
{
    __shared__ unsigned int s_iou[2 * CH * LDW];      // 32.9 KB
    __shared__ unsigned long long s_part[NN][17];     // 13.6 KB
    __shared__ float s_area[NN];                      // 400 B

    const int b = blockIdx.y;
    const int t = threadIdx.x;
    const int p0 = blockIdx.x * 512 + t;
    const int p1 = p0 + 256;
    const bool v0 = p0 < PP;
    const bool v1 = p1 < PP;
    const int pc0 = v0 ? p0 : (PP - 1);
    const int pc1 = v1 ? p1 : (PP - 1);

    // wave-uniform base: compiler scalarizes these loads (s_load_dwordx4)
    const float4* __restrict__ gtb =
        reinterpret_cast<const float4*>(gt) + b * NN;

    if (t < NN) {
        float4 g = gtb[t];
        s_area[t] = (g.z - g.x) * (g.w - g.y);
    }

    const float4 prA = reinterpret_cast<const float4*>(priors)[pc0];
    const float4 prB = reinterpret_cast<const float4*>(priors)[pc1];
    const float ax1 = prA.x - prA.z * 0.5f, ay1 = prA.y - prA.w * 0.5f;
    const float ax2 = prA.x + prA.z * 0.5f, ay2 = prA.y + prA.w * 0.5f;
    const float areaA = (ax2 - ax1) * (ay2 - ay1);
    const float bx1 = prB.x - prB.z * 0.5f, by1 = prB.y - prB.w * 0.5f;
    const float bx2 = prB.x + prB.z * 0.5f, by2 = prB.y + prB.w * 0.5f;
    const float areaB = (bx2 - bx1) * (by2 - by1);

    float bo0 = -1.0f, bo1 = -1.0f;
    int bj0 = 0, bj1 = 0;

    __syncthreads();   // s_area ready

    for (int jc = 0; jc < NN; jc += CH) {
        const int nr = (NN - jc) < CH ? (NN - jc) : CH;

        #pragma unroll
        for (int jj = 0; jj < CH; ++jj) {
            if (jj >= nr) break;
            float4 g = gtb[jc + jj];                 // uniform -> SGPRs
            float area_a = s_area[jc + jj];          // broadcast ds_read

            float l0 = fmaxf(g.x, ax1), t0 = fmaxf(g.y, ay1);
            float r0 = fminf(g.z, ax2), b0 = fminf(g.w, ay2);
            float w0 = fmaxf(r0 - l0, 0.0f), h0 = fmaxf(b0 - t0, 0.0f);
            float in0 = w0 * h0;
            float iou0 = in0 / (area_a + areaA - in0 + 1e-6f);

            float l1 = fmaxf(g.x, bx1), t1 = fmaxf(g.y, by1);
            float r1 = fminf(g.z, bx2), b1 = fminf(g.w, by2);
            float w1 = fmaxf(r1 - l1, 0.0f), h1 = fmaxf(b1 - t1, 0.0f);
            float in1 = w1 * h1;
            float iou1 = in1 / (area_a + areaB - in1 + 1e-6f);

            if (iou0 > bo0) { bo0 = iou0; bj0 = jc + jj; }
            if (iou1 > bo1) { bo1 = iou1; bj1 = jc + jj; }
            s_iou[jj * LDW + t] = __float_as_uint(iou0);  // iou>=0
            s_iou[CH * LDW + jj * LDW + t] = __float_as_uint(iou1);
        }
        __syncthreads();

        // phase A: 16 threads per row, 16 ascending-p cols per strip, merge
        {
            const int r = t & 15;
            const int s = t >> 4;
            if (r < nr) {
                const unsigned int* rowA = s_iou + r * LDW + s * 16;
                unsigned int ba = rowA[0]; int ia = 0;
                #pragma unroll
                for (int i = 1; i < 16; ++i) {
                    unsigned int v = rowA[i];
                    if (v > ba) { ba = v; ia = i; }   // strict > = min p
                }
                const unsigned int* rowB = rowA + CH * LDW;
                unsigned int bb = rowB[0]; int ib = 0;
                #pragma unroll
                for (int i = 1; i < 16; ++i) {
                    unsigned int v = rowB[i];
                    if (v > bb) { bb = v; ib = i; }
                }
                int pwA = blockIdx.x * 512 + s * 16 + ia;
                int pwB = blockIdx.x * 512 + 256 + s * 16 + ib;
                unsigned long long kA = ((unsigned long long)ba << 32) |
                                        (unsigned int)(~pwA);
                unsigned long long kB = ((unsigned long long)bb << 32) |
                                        (unsigned int)(~pwB);
                s_part[jc + r][s] = kA > kB ? kA : kB;  // ~p: min-p ties
            }
        }
        __syncthreads();   // s_iou reusable next chunk; s_part visible
    }

    // phase B: merge 16 segment partials per gt; plain store (or atomic)
    if (t < NN) {
        unsigned long long best = s_part[t][0];
        #pragma unroll
        for (int s = 1; s < 16; ++s) {
            unsigned long long k = s_part[t][s];
            if (k > best) best = k;                   // ~p breaks iou ties
        }
        if (USE_PART) {
            red[((size_t)b * NBK + blockIdx.x) * NN + t] = best;
        } else {
            atomicMax(&red[b * NN + t], best);
        }
    }
    if (v0) m8[b * PP + p0] =
        (unsigned char)(bj0 | ((bo0 < 0.5f) ? 0x80 : 0));
    if (v1) m8[b * PP + p1] =
        (unsigned char)(bj1 | ((bo1 < 0.5f) ? 0x80 : 0));
}

// -------------------------------------------------------------------------
// Kernel 2: reduce the NBK per-block row keys (USE_PART) or read gkey,
// scatter forced matches into LDS (max j = last-write-wins, matching the
// reference scatter), then encode.
// -------------------------------------------------------------------------
template <bool USE_PART>
__global__ __launch_bounds__(256) void k_encode(
    const float* __restrict__ gt,        // [B,N,4]
    const int*   __restrict__ labels,    // [B,N]
    const float* __restrict__ priors,    // [P,4]
    const unsigned long long* __restrict__ red,   // part or gkey
    const unsigned char* __restrict__ m8,         // [B,P]
    float* __restrict__ loc_out,         // [B,P,4]
    float* __restrict__ conf_out)        // [B,P]
{
    __shared__ int s_forced[256];        // local p -> forced gt j (-1 none)

    const int b = blockIdx.y;
    const int t = threadIdx.x;
    const int p = blockIdx.x * 256 + t;

    s_forced[t] = -1;
    __syncthreads();
    if (t < NN) {
        unsigned long long best;
        if (USE_PART) {
            const unsigned long long* q = red + (size_t)b * NBK * NN + t;
            best = q[0];
            #pragma unroll 6
            for (int bx = 1; bx < NBK; ++bx) {
                unsigned long long k = q[(size_t)bx * NN];
                if (k > best) best = k;
            }
        } else {
            best = red[b * NN + t];
        }
        int kp = (int)~(unsigned int)(best & 0xFFFFFFFFull);
        int lp = kp - blockIdx.x * 256;
        if ((unsigned)lp < 256u) atomicMax(&s_forced[lp], t);
    }
    __syncthreads();

    if (p >= PP) return;
    const int forced_j = s_forced[t];

    const unsigned char m = m8[b * PP + p];
    const int j    = (forced_j >= 0) ? forced_j : (m & 0x7f);
    const int lab  = labels[b * NN + j];
    const int conf = (forced_j < 0 && (m & 0x80)) ? 0 : (lab + 1);

    const float4 pr = reinterpret_cast<const float4*>(priors)[p];
    const float4 g  = reinterpret_cast<const float4*>(gt)[b * NN + j];
    const float mcx = (g.x + g.z) * 0.5f;
    const float mcy = (g.y + g.w) * 0.5f;
    const float mw  = fmaxf(g.z - g.x, 1e-6f);
    const float mh  = fmaxf(g.w - g.y, 1e-6f);
    const float gcx = (mcx - pr.x) / (0.1f * pr.z);
    const float gcy = (mcy - pr.y) / (0.1f * pr.w);
    const float gw  = logf(mw / pr.z) / 0.2f;
    const float gh  = logf(mh / pr.w) / 0.2f;

    reinterpret_cast<float4*>(loc_out)[b * PP + p] =
        make_float4(gcx, gcy, gw, gh);
    conf_out[b * PP + p] = (float)conf;
}

extern "C" void kernel_launch(void* const* d_in, const int* in_sizes, int n_in,
                              void* d_out, int out_size, void* d_ws, size_t ws_size,
                              hipStream_t stream) {
    const float* gt     = (const float*)d_in[0];  // [32,100,4] f32
    const int*   labels = (const int*)  d_in[1];  // [32,100] i32
    const float* priors = (const float*)d_in[2];  // [8732,4] f32

    float* loc  = (float*)d_out;                         // [32,8732,4]
    float* conf = (float*)d_out + (size_t)BB * PP * 4;   // [32,8732]

    const size_t part_bytes = (size_t)BB * NBK * NN * 8;   // 460,800
    const size_t m8_bytes   = (size_t)BB * PP;             // 279,424
    dim3 giou(NBK, BB);
    dim3 genc(NBX, BB);

    if (ws_size >= part_bytes + m8_bytes) {
        // atomic-free path: per-block partial keys, no memset dispatch
        unsigned long long* part = (unsigned long long*)d_ws;
        unsigned char* m8 = (unsigned char*)d_ws + part_bytes;
        k_iou_pass<true><<<giou, 256, 0, stream>>>(gt, priors, part, m8);
        k_encode<true><<<genc, 256, 0, stream>>>(gt, labels, priors, part,
                                                 m8, loc, conf);
    } else {
        // fallback: gkey + atomicMax (needs zeroed keys)
        unsigned long long* gkey = (unsigned long long*)d_ws;        // [32,100]
        unsigned char* m8 = (unsigned char*)d_ws + (size_t)BB * NN * 8;
        hipMemsetAsync(gkey, 0, (size_t)BB * NN * 8, stream);
        k_iou_pass<false><<<giou, 256, 0, stream>>>(gt, priors, gkey, m8);
        k_encode<false><<<genc, 256, 0, stream>>>(gt, labels, priors, gkey,
                                                  m8, loc, conf);
    }
}

// Round 9
// 97.365 us; speedup vs baseline: 1.0681x; 1.0296x over previous
//
#include <hip/hip_runtime.h>

// Disable FMA contraction so float rounding matches the numpy reference
// op-for-op (threshold compares at 0.5 and argmax ties depend on it).
#pragma clang fp contract(off)

#define BB 32     // batch
#define NN 100    // gt boxes per image
#define PP 8732   // priors
#define HJ 50     // gt boxes per j-half
#define CHH 8     // j-chunk per half (16 transpose rows per chunk)
#define LDW 129   // padded row stride (u32) -> 2-way banks only (free)
#define NBK 69    // k_iou blocks along the prior axis (128-wide strips)
#define NBX 35    // k_encode blocks along the prior axis (256-wide)

// -------------------------------------------------------------------------
// Kernel 1: block = 128 priors x 2 j-halves. Thread t owns prior
// p = bx*128 + (t&127) and gts j in [half*50, half*50+50), half = t>>7
// (wave-uniform, so gtb[j] is one coalesced 16B L1-hit load per wave).
// This doubles resident waves/CU (28 vs 17.5) for the latency-bound loop.
//  - column max/argmax per (prior,half) in regs (strict > = first
//    occurrence); halves merged via u64 (iou<<32)|~j keys in LDS.
//  - row max: per 8-j chunk each half writes its 8 transpose rows
//    (2-way banks = free); phase A = 16 rows x 16 segs x 8 ascending-p
//    cols (strict > = min p); phase B merges 16 segs -> plain store of
//    (iou<<32)|~p per block (USE_PART) or atomicMax (fallback).
// Out-of-range lanes compute the real IoU of prior PP-1: duplicate
// columns tie with p=8731's value and lose the ~p tie-break, so no
// pw >= PP can win (verified rounds 5-8).
// -------------------------------------------------------------------------
template <bool USE_PART>
__global__ __launch_bounds__(256) void k_iou_pass(
    const float* __restrict__ gt,        // [B,N,4] xyxy
    const float* __restrict__ priors,    // [P,4] cxcywh
    unsigned long long* __restrict__ red,   // part [B][NBK][NN] or gkey [B][N]
    unsigned char* __restrict__ m8)         // [B,P]: best_j | (bg?0x80:0)
{
    __shared__ unsigned int s_iou[2 * CHH * LDW];     // 16 rows, 8.3 KB
    __shared__ unsigned long long s_part[NN][17];     // 13.6 KB

    const int b    = blockIdx.y;
    const int t    = threadIdx.x;
    const int tc   = t & 127;
    const int half = t >> 7;             // wave-uniform (waves 0,1 vs 2,3)
    const int p    = blockIdx.x * 128 + tc;
    const bool valid = p < PP;
    const int pc = valid ? p : (PP - 1);

    const float4* __restrict__ gtb =
        reinterpret_cast<const float4*>(gt) + b * NN;

    const float4 pr = reinterpret_cast<const float4*>(priors)[pc];
    const float px1 = pr.x - pr.z * 0.5f;
    const float py1 = pr.y - pr.w * 0.5f;
    const float px2 = pr.x + pr.z * 0.5f;
    const float py2 = pr.y + pr.w * 0.5f;
    const float area_b = (px2 - px1) * (py2 - py1);

    float bo = -1.0f;
    int bj = half * HJ;

    for (int jc = 0; jc < HJ; jc += CHH) {
        const int nr = (HJ - jc) < CHH ? (HJ - jc) : CHH;

        #pragma unroll
        for (int jj = 0; jj < CHH; ++jj) {
            if (jj >= nr) break;
            const int j = half * HJ + jc + jj;       // wave-uniform
            float4 g = gtb[j];                       // 1 coalesced 16B load
            float area_a = (g.z - g.x) * (g.w - g.y);
            float ltx = fmaxf(g.x, px1), lty = fmaxf(g.y, py1);
            float rbx = fminf(g.z, px2), rby = fminf(g.w, py2);
            float w = fmaxf(rbx - ltx, 0.0f), h = fmaxf(rby - lty, 0.0f);
            float inter = w * h;
            float iou = inter / (area_a + area_b - inter + 1e-6f);
            if (iou > bo) { bo = iou; bj = j; }      // first occurrence
            s_iou[(half * CHH + jj) * LDW + tc] = __float_as_uint(iou);
        }
        __syncthreads();

        // phase A: 16 rows x 16 segs, 8 ascending-p cols per thread
        {
            const int r  = t & 15;       // transpose row
            const int s  = t >> 4;       // segment (cols s*8 .. s*8+7)
            const int rr = r & 7;        // row within its half
            if (rr < nr) {
                const unsigned int* row = s_iou + r * LDW + s * 8;
                unsigned int bb = row[0];
                int bi = 0;
                #pragma unroll
                for (int i = 1; i < 8; ++i) {
                    unsigned int v = row[i];
                    if (v > bb) { bb = v; bi = i; }   // strict > = min p
                }
                int pw = blockIdx.x * 128 + s * 8 + bi;
                int jrow = (r >> 3) * HJ + jc + rr;   // global gt index
                s_part[jrow][s] = ((unsigned long long)bb << 32) |
                                  (unsigned int)(~pw);
            }
        }
        __syncthreads();   // s_iou reusable next chunk; s_part visible
    }

    // column-max merge across the two j-halves (alias s_iou as u64[128])
    unsigned long long* s_mrg = (unsigned long long*)s_iou;
    unsigned long long ck = ((unsigned long long)__float_as_uint(bo) << 32) |
                            (unsigned int)(~bj);
    if (half) s_mrg[tc] = ck;
    __syncthreads();
    if (!half && valid) {
        unsigned long long o = s_mrg[tc];
        if (o > ck) ck = o;              // max iou, tie -> min j (~j max)
        float fo = __uint_as_float((unsigned int)(ck >> 32));
        int fj = (int)~(unsigned int)ck;
        m8[b * PP + p] = (unsigned char)(fj | ((fo < 0.5f) ? 0x80 : 0));
    }

    // phase B: merge 16 segment partials per gt; plain store (or atomic)
    if (t < NN) {
        unsigned long long best = s_part[t][0];
        #pragma unroll
        for (int s = 1; s < 16; ++s) {
            unsigned long long k = s_part[t][s];
            if (k > best) best = k;                   // ~p breaks iou ties
        }
        if (USE_PART) {
            red[((size_t)b * NBK + blockIdx.x) * NN + t] = best;
        } else {
            atomicMax(&red[b * NN + t], best);
        }
    }
}

// -------------------------------------------------------------------------
// Kernel 2: reduce the NBK per-block row keys (USE_PART) or read gkey,
// scatter forced matches into LDS (max j = last-write-wins, matching the
// reference scatter), then encode.
// -------------------------------------------------------------------------
template <bool USE_PART>
__global__ __launch_bounds__(256) void k_encode(
    const float* __restrict__ gt,        // [B,N,4]
    const int*   __restrict__ labels,    // [B,N]
    const float* __restrict__ priors,    // [P,4]
    const unsigned long long* __restrict__ red,   // part or gkey
    const unsigned char* __restrict__ m8,         // [B,P]
    float* __restrict__ loc_out,         // [B,P,4]
    float* __restrict__ conf_out)        // [B,P]
{
    __shared__ int s_forced[256];        // local p -> forced gt j (-1 none)

    const int b = blockIdx.y;
    const int t = threadIdx.x;
    const int p = blockIdx.x * 256 + t;

    s_forced[t] = -1;
    __syncthreads();
    if (t < NN) {
        unsigned long long best;
        if (USE_PART) {
            const unsigned long long* q = red + (size_t)b * NBK * NN + t;
            best = q[0];
            #pragma unroll 4
            for (int bx = 1; bx < NBK; ++bx) {
                unsigned long long k = q[(size_t)bx * NN];
                if (k > best) best = k;
            }
        } else {
            best = red[b * NN + t];
        }
        int kp = (int)~(unsigned int)(best & 0xFFFFFFFFull);
        int lp = kp - blockIdx.x * 256;
        if ((unsigned)lp < 256u) atomicMax(&s_forced[lp], t);
    }
    __syncthreads();

    if (p >= PP) return;
    const int forced_j = s_forced[t];

    const unsigned char m = m8[b * PP + p];
    const int j    = (forced_j >= 0) ? forced_j : (m & 0x7f);
    const int lab  = labels[b * NN + j];
    const int conf = (forced_j < 0 && (m & 0x80)) ? 0 : (lab + 1);

    const float4 pr = reinterpret_cast<const float4*>(priors)[p];
    const float4 g  = reinterpret_cast<const float4*>(gt)[b * NN + j];
    const float mcx = (g.x + g.z) * 0.5f;
    const float mcy = (g.y + g.w) * 0.5f;
    const float mw  = fmaxf(g.z - g.x, 1e-6f);
    const float mh  = fmaxf(g.w - g.y, 1e-6f);
    const float gcx = (mcx - pr.x) / (0.1f * pr.z);
    const float gcy = (mcy - pr.y) / (0.1f * pr.w);
    const float gw  = logf(mw / pr.z) / 0.2f;
    const float gh  = logf(mh / pr.w) / 0.2f;

    reinterpret_cast<float4*>(loc_out)[b * PP + p] =
        make_float4(gcx, gcy, gw, gh);
    conf_out[b * PP + p] = (float)conf;
}

extern "C" void kernel_launch(void* const* d_in, const int* in_sizes, int n_in,
                              void* d_out, int out_size, void* d_ws, size_t ws_size,
                              hipStream_t stream) {
    const float* gt     = (const float*)d_in[0];  // [32,100,4] f32
    const int*   labels = (const int*)  d_in[1];  // [32,100] i32
    const float* priors = (const float*)d_in[2];  // [8732,4] f32

    float* loc  = (float*)d_out;                         // [32,8732,4]
    float* conf = (float*)d_out + (size_t)BB * PP * 4;   // [32,8732]

    const size_t part_bytes = (size_t)BB * NBK * NN * 8;   // 1,766,400
    const size_t m8_bytes   = (size_t)BB * PP;             // 279,424
    dim3 giou(NBK, BB);
    dim3 genc(NBX, BB);

    if (ws_size >= part_bytes + m8_bytes) {
        // atomic-free path: per-block partial keys, no memset dispatch
        unsigned long long* part = (unsigned long long*)d_ws;
        unsigned char* m8 = (unsigned char*)d_ws + part_bytes;
        k_iou_pass<true><<<giou, 256, 0, stream>>>(gt, priors, part, m8);
        k_encode<true><<<genc, 256, 0, stream>>>(gt, labels, priors, part,
                                                 m8, loc, conf);
    } else {
        // fallback: gkey + atomicMax (needs zeroed keys)
        unsigned long long* gkey = (unsigned long long*)d_ws;        // [32,100]
        unsigned char* m8 = (unsigned char*)d_ws + (size_t)BB * NN * 8;
        hipMemsetAsync(gkey, 0, (size_t)BB * NN * 8, stream);
        k_iou_pass<false><<<giou, 256, 0, stream>>>(gt, priors, gkey, m8);
        k_encode<false><<<genc, 256, 0, stream>>>(gt, labels, priors, gkey,
                                                  m8, loc, conf);
    }
}

// Round 10
// 97.109 us; speedup vs baseline: 1.0709x; 1.0026x over previous
//
#include <hip/hip_runtime.h>

// Disable FMA contraction so float rounding matches the numpy reference
// op-for-op (threshold compares at 0.5 and argmax ties depend on it).
#pragma clang fp contract(off)

#define BB 32     // batch
#define NN 100    // gt boxes per image
#define PP 8732   // priors
#define CH 16     // j-chunk for the transposed row-max reduce
#define LDW 260   // padded row stride (u32): 16B-aligned segs, 2-way banks
#define NBX 35    // blocks along the prior axis (256-wide)

// -------------------------------------------------------------------------
// Kernel 1 (round-6 skeleton, LDS ops widened): thread owns prior p of
// batch b.
//  - GT corners via wave-uniform scalar loads; area_a via LDS prologue.
//  - Out-of-range lanes compute the real IoU of prior PP-1: duplicate
//    columns tie with p=8731's value and lose the (iou<<32)|~p min-p
//    tie-break, so no pw >= PP can win (verified rounds 5-9).
//  - column max/argmax over gts (strict > = first occurrence) -> m8 byte
//  - row max: chunked LDS transpose; j-loop writes 1 ds_write_b32/j
//    (stride-1, 2-way banks = free); phase A reads its 16 ascending-p
//    cols as 4 x ds_read_b128 (LDW=260 makes every seg 16B-aligned);
//    phase B merges 16 segs via 8 x ulonglong2 reads and plain-stores the
//    per-block key to part[b][bx][j] (USE_PART) or atomicMax (fallback).
// -------------------------------------------------------------------------
template <bool USE_PART>
__global__ __launch_bounds__(256) void k_iou_pass(
    const float* __restrict__ gt,        // [B,N,4] xyxy
    const float* __restrict__ priors,    // [P,4] cxcywh
    unsigned long long* __restrict__ red,   // part [B][NBX][NN] or gkey [B][N]
    unsigned char* __restrict__ m8)         // [B,P]: best_j | (bg?0x80:0)
{
    __shared__ unsigned int s_iou[CH * LDW];          // 16.6 KB
    __shared__ unsigned long long s_part[NN][18];     // 14.4 KB, 16B rows
    __shared__ float s_area[NN];                      // 400 B

    const int b = blockIdx.y;
    const int t = threadIdx.x;
    const int p = blockIdx.x * 256 + t;
    const bool valid = p < PP;
    const int pc = valid ? p : (PP - 1);

    // wave-uniform base: compiler scalarizes these loads (s_load_dwordx4)
    const float4* __restrict__ gtb =
        reinterpret_cast<const float4*>(gt) + b * NN;

    if (t < NN) {
        float4 g = gtb[t];
        s_area[t] = (g.z - g.x) * (g.w - g.y);
    }

    const float4 pr = reinterpret_cast<const float4*>(priors)[pc];
    const float px1 = pr.x - pr.z * 0.5f;
    const float py1 = pr.y - pr.w * 0.5f;
    const float px2 = pr.x + pr.z * 0.5f;
    const float py2 = pr.y + pr.w * 0.5f;
    const float area_b = (px2 - px1) * (py2 - py1);

    float best_ov = -1.0f;
    int best_j = 0;

    __syncthreads();   // s_area ready

    for (int jc = 0; jc < NN; jc += CH) {
        const int nr = (NN - jc) < CH ? (NN - jc) : CH;

        #pragma unroll
        for (int jj = 0; jj < CH; ++jj) {
            if (jj >= nr) break;
            float4 g = gtb[jc + jj];                 // uniform -> SGPRs
            float area_a = s_area[jc + jj];          // broadcast ds_read
            float ltx = fmaxf(g.x, px1), lty = fmaxf(g.y, py1);
            float rbx = fminf(g.z, px2), rby = fminf(g.w, py2);
            float w = fmaxf(rbx - ltx, 0.0f), h = fmaxf(rby - lty, 0.0f);
            float inter = w * h;
            float iou = inter / (area_a + area_b - inter + 1e-6f);
            if (iou > best_ov) { best_ov = iou; best_j = jc + jj; }
            s_iou[jj * LDW + t] = __float_as_uint(iou);  // iou>=0: uint order
        }
        __syncthreads();

        // phase A: 16 threads per row, 16 ascending-p cols as 4 x b128
        {
            const int r = t & 15;
            const int s = t >> 4;
            if (r < nr) {
                const uint4* row = reinterpret_cast<const uint4*>(
                    s_iou + r * LDW + s * 16);       // 16B-aligned (LDW=260)
                uint4 q0 = row[0], q1 = row[1], q2 = row[2], q3 = row[3];
                unsigned int c[16] = {q0.x, q0.y, q0.z, q0.w,
                                      q1.x, q1.y, q1.z, q1.w,
                                      q2.x, q2.y, q2.z, q2.w,
                                      q3.x, q3.y, q3.z, q3.w};
                unsigned int bb = c[0];
                int bi = 0;
                #pragma unroll
                for (int i = 1; i < 16; ++i)
                    if (c[i] > bb) { bb = c[i]; bi = i; }  // strict > = min p
                int pw = blockIdx.x * 256 + s * 16 + bi;
                s_part[jc + r][s] = ((unsigned long long)bb << 32) |
                                    (unsigned int)(~pw);
            }
        }
        __syncthreads();   // s_iou reusable next chunk; s_part visible
    }

    // phase B: merge 16 segment partials per gt via 8 x ulonglong2 reads
    if (t < NN) {
        const ulonglong2* q =
            reinterpret_cast<const ulonglong2*>(&s_part[t][0]);  // 16B-aligned
        unsigned long long best = 0ull;
        #pragma unroll
        for (int s = 0; s < 8; ++s) {
            ulonglong2 kk = q[s];
            if (kk.x > best) best = kk.x;             // ~p breaks iou ties
            if (kk.y > best) best = kk.y;
        }
        if (USE_PART) {
            red[((size_t)b * NBX + blockIdx.x) * NN + t] = best;
        } else {
            atomicMax(&red[b * NN + t], best);
        }
    }
    if (valid) {
        m8[b * PP + p] =
            (unsigned char)(best_j | ((best_ov < 0.5f) ? 0x80 : 0));
    }
}

// -------------------------------------------------------------------------
// Kernel 2: reduce the NBX per-block row keys (USE_PART) or read gkey,
// scatter forced matches into LDS (max j = last-write-wins, matching the
// reference scatter), then encode. Identical to round 6.
// -------------------------------------------------------------------------
template <bool USE_PART>
__global__ __launch_bounds__(256) void k_encode(
    const float* __restrict__ gt,        // [B,N,4]
    const int*   __restrict__ labels,    // [B,N]
    const float* __restrict__ priors,    // [P,4]
    const unsigned long long* __restrict__ red,   // part or gkey
    const unsigned char* __restrict__ m8,         // [B,P]
    float* __restrict__ loc_out,         // [B,P,4]
    float* __restrict__ conf_out)        // [B,P]
{
    __shared__ int s_forced[256];        // local p -> forced gt j (-1 none)

    const int b = blockIdx.y;
    const int t = threadIdx.x;
    const int p = blockIdx.x * 256 + t;

    s_forced[t] = -1;
    __syncthreads();
    if (t < NN) {
        unsigned long long best;
        if (USE_PART) {
            const unsigned long long* q = red + (size_t)b * NBX * NN + t;
            best = q[0];
            #pragma unroll 5
            for (int bx = 1; bx < NBX; ++bx) {
                unsigned long long k = q[(size_t)bx * NN];
                if (k > best) best = k;
            }
        } else {
            best = red[b * NN + t];
        }
        int kp = (int)~(unsigned int)(best & 0xFFFFFFFFull);
        int lp = kp - blockIdx.x * 256;
        if ((unsigned)lp < 256u) atomicMax(&s_forced[lp], t);
    }
    __syncthreads();

    if (p >= PP) return;
    const int forced_j = s_forced[t];

    const unsigned char m = m8[b * PP + p];
    const int j    = (forced_j >= 0) ? forced_j : (m & 0x7f);
    const int lab  = labels[b * NN + j];
    const int conf = (forced_j < 0 && (m & 0x80)) ? 0 : (lab + 1);

    const float4 pr = reinterpret_cast<const float4*>(priors)[p];
    const float4 g  = reinterpret_cast<const float4*>(gt)[b * NN + j];
    const float mcx = (g.x + g.z) * 0.5f;
    const float mcy = (g.y + g.w) * 0.5f;
    const float mw  = fmaxf(g.z - g.x, 1e-6f);
    const float mh  = fmaxf(g.w - g.y, 1e-6f);
    const float gcx = (mcx - pr.x) / (0.1f * pr.z);
    const float gcy = (mcy - pr.y) / (0.1f * pr.w);
    const float gw  = logf(mw / pr.z) / 0.2f;
    const float gh  = logf(mh / pr.w) / 0.2f;

    reinterpret_cast<float4*>(loc_out)[b * PP + p] =
        make_float4(gcx, gcy, gw, gh);
    conf_out[b * PP + p] = (float)conf;
}

extern "C" void kernel_launch(void* const* d_in, const int* in_sizes, int n_in,
                              void* d_out, int out_size, void* d_ws, size_t ws_size,
                              hipStream_t stream) {
    const float* gt     = (const float*)d_in[0];  // [32,100,4] f32
    const int*   labels = (const int*)  d_in[1];  // [32,100] i32
    const float* priors = (const float*)d_in[2];  // [8732,4] f32

    float* loc  = (float*)d_out;                         // [32,8732,4]
    float* conf = (float*)d_out + (size_t)BB * PP * 4;   // [32,8732]

    const size_t part_bytes = (size_t)BB * NBX * NN * 8;   // 896,000
    const size_t m8_bytes   = (size_t)BB * PP;             // 279,424
    dim3 grid(NBX, BB);

    if (ws_size >= part_bytes + m8_bytes) {
        // atomic-free path: per-block partial keys, no memset dispatch
        unsigned long long* part = (unsigned long long*)d_ws;
        unsigned char* m8 = (unsigned char*)d_ws + part_bytes;
        k_iou_pass<true><<<grid, 256, 0, stream>>>(gt, priors, part, m8);
        k_encode<true><<<grid, 256, 0, stream>>>(gt, labels, priors, part,
                                                 m8, loc, conf);
    } else {
        // fallback: gkey + atomicMax (needs zeroed keys)
        unsigned long long* gkey = (unsigned long long*)d_ws;        // [32,100]
        unsigned char* m8 = (unsigned char*)d_ws + (size_t)BB * NN * 8;
        hipMemsetAsync(gkey, 0, (size_t)BB * NN * 8, stream);
        k_iou_pass<false><<<grid, 256, 0, stream>>>(gt, priors, gkey, m8);
        k_encode<false><<<grid, 256, 0, stream>>>(gt, labels, priors, gkey,
                                                  m8, loc, conf);
    }
}